// Round 19
// baseline (376.595 us; speedup 1.0000x reference)
//
#include <hip/hip_runtime.h>
#include <math.h>

// Factorized GCN: A_hat = D^-1/2 (A+I) D^-1/2. All aggregations are
// prescale(rows by dinv) -> pure gather-sum over CSR cols -> postscale by dinv.
// CSR rows RANK-PERMUTED by class c=i&7; node-indexed rows[i]=(rs,re).
// BF16 storage on all gathered/streamed operands (xp/hA/g); fp32 accumulation.
// gemmz via bf16 MFMA (W2 pre-packed B-frags). aggH half-wave (occupancy >
// per-wave MLP in this latency regime — r15/16). r19: CSR build is now
// bucket (single edge pass -> 8 class-contiguous segments) + fill_seg
// (class blocks read only their segment): ~100 MB of fill streaming -> ~38 MB,
// all cursor/col atomics & writes XCD-local.

#define CHUNK 2048

using short8 = __attribute__((ext_vector_type(8))) short;
using floatx4 = __attribute__((ext_vector_type(4))) float;

__device__ __forceinline__ int rankof(int i, int nq, int nr) {
  int c = i & 7;
  return c * nq + min(c, nr) + (i >> 3);
}
__device__ __forceinline__ unsigned int f2bf(float f) {   // RNE
  unsigned int u = __float_as_uint(f);
  return ((u + 0x7fff + ((u >> 16) & 1)) >> 16);
}
__device__ __forceinline__ float bflo(unsigned int u) { return __uint_as_float(u << 16); }
__device__ __forceinline__ float bfhi(unsigned int u) { return __uint_as_float(u & 0xffff0000u); }

// ---------------- CSR build: bucket pass (one read of the edge list) ----------------
// Appends (dst,src) into 8 class-contiguous segments; also rank-space degree count.

__global__ __launch_bounds__(256) void bucket_kernel(const int* __restrict__ src,
    const int* __restrict__ dst, int* cnt_rank, int* clsCount,
    uint2* __restrict__ ebuf, int segCap, int E, int nq, int nr) {
  __shared__ int cnt[8];
  __shared__ int base[8];
  int t = threadIdx.x;
  if (t < 8) cnt[t] = 0;
  __syncthreads();
  int e0 = blockIdx.x * CHUNK;
  int d[8], s[8], off[8];
#pragma unroll
  for (int j = 0; j < 8; ++j) {
    int e = e0 + j * 256 + t;
    if (e < E) {
      d[j] = dst[e]; s[j] = src[e];
      off[j] = atomicAdd(&cnt[d[j] & 7], 1);
    } else d[j] = -1;
  }
  __syncthreads();
  if (t < 8) base[t] = atomicAdd(&clsCount[t], cnt[t]);
  __syncthreads();
#pragma unroll
  for (int j = 0; j < 8; ++j) {
    if (d[j] >= 0) {
      int c = d[j] & 7;
      ebuf[(size_t)c * segCap + base[c] + off[j]] =
          make_uint2((unsigned)d[j], (unsigned)s[j]);
      atomicAdd(&cnt_rank[rankof(d[j], nq, nr)], 1);
    }
  }
}

// dinv + per-block rank-order sums -> bsum; xp = bf16(dinv_i * x_i), 16 bf16/row (32B)
__global__ void dinv_bsum_pad_kernel(const int* __restrict__ cnt_rank,
                                     float* __restrict__ dinv, int* bsum,
                                     const float* __restrict__ x,
                                     unsigned short* __restrict__ xp, int N, int nq, int nr) {
  __shared__ int s[256];
  int t = threadIdx.x;
  int gid = blockIdx.x * 256 + t;
  s[t] = (gid < N) ? cnt_rank[gid] : 0;     // scan basis: rank-order, coalesced
  if (gid < N) {
    int c = cnt_rank[rankof(gid, nq, nr)];  // this node's in-degree
    float di = 1.0f / sqrtf((float)c + 1.0f);
    dinv[gid] = di;
    const float* xr = x + (size_t)gid * 9;
    unsigned int w0 = f2bf(xr[0] * di) | (f2bf(xr[1] * di) << 16);
    unsigned int w1 = f2bf(xr[2] * di) | (f2bf(xr[3] * di) << 16);
    unsigned int w2 = f2bf(xr[4] * di) | (f2bf(xr[5] * di) << 16);
    unsigned int w3 = f2bf(xr[6] * di) | (f2bf(xr[7] * di) << 16);
    unsigned int w4 = f2bf(xr[8] * di);
    uint4* xo = (uint4*)(xp + (size_t)gid * 16);
    xo[0] = make_uint4(w0, w1, w2, w3);
    xo[1] = make_uint4(w4, 0u, 0u, 0u);
  }
  __syncthreads();
  for (int off = 128; off > 0; off >>= 1) {
    if (t < off) s[t] += s[t + off];
    __syncthreads();
  }
  if (t == 0) bsum[blockIdx.x] = s[0];
}

// Scan over RANK space -> rank-indexed cursor (fill) + NODE-indexed rows[i].
// Block 0: v = W3@lin_w, c0 = b3.lin_w + lin_b; zero g row N (gemmz pad row).
// Blocks 1..8: pack W2 -> bf16 B-fragment layout W2p[ntile][kstep][lane][8].
__global__ void rowptr_vc0_kernel(const int* __restrict__ indeg, const int* __restrict__ bsum,
                                  int2* __restrict__ rows, int* cursor, int N, int E,
                                  int nq, int nr,
                                  const float* __restrict__ W3, const float* __restrict__ b3,
                                  const float* __restrict__ lin_w, const float* __restrict__ lin_b,
                                  const float* __restrict__ W2, unsigned short* __restrict__ W2p,
                                  unsigned short* __restrict__ g,
                                  float* v, float* c0) {
  __shared__ int ps[256];
  __shared__ int s[256];
  int t = threadIdx.x;
  int pref = 0;
  for (int q = t; q < blockIdx.x; q += 256) pref += bsum[q];
  ps[t] = pref;
  __syncthreads();
  for (int off = 128; off > 0; off >>= 1) {
    if (t < off) ps[t] += ps[t + off];
    __syncthreads();
  }
  int base = ps[0];
  int r = blockIdx.x * 256 + t;
  int val = (r < N) ? indeg[r] : 0;
  s[t] = val;
  __syncthreads();
  for (int off = 1; off < 256; off <<= 1) {
    int x = (t >= off) ? s[t - off] : 0;
    __syncthreads();
    s[t] += x;
    __syncthreads();
  }
  int excl = s[t] - val + base;
  if (r < N) {
    cursor[r] = excl;                       // rank-indexed fill cursor
    int c = 0;                              // invert rank -> node id
#pragma unroll
    for (int cc = 1; cc < 8; ++cc) {
      int b = cc * nq + min(cc, nr);
      if (r >= b) c = cc;
    }
    int iinv = ((r - (c * nq + min(c, nr))) << 3) | c;
    rows[iinv] = make_int2(excl, excl + val);  // node-indexed (scattered, once)
  }
  if (blockIdx.x == 0) {
    if (t < 64) ((unsigned int*)g)[(size_t)N * 64 + t] = 0u;  // zero pad row N
    if (t < 128) {
      float sv = 0.0f;
      for (int c = 0; c < 128; ++c) sv = fmaf(W3[t * 128 + c], lin_w[c], sv);
      v[t] = sv;
    } else if (t == 128) {
      float sv = 0.0f;
      for (int c = 0; c < 128; ++c) sv = fmaf(b3[c], lin_w[c], sv);
      c0[0] = sv + lin_b[0];
    }
  } else if (blockIdx.x <= 8) {
    // B-frag pack: lane holds W2[k][n], n = ntile*16 + (lane&15),
    // k = kstep*32 + (lane>>4)*8 + j, j=0..7
    int ntile = blockIdx.x - 1;
    int kstep = t >> 6, lane = t & 63;
    int n = ntile * 16 + (lane & 15);
    int k0 = kstep * 32 + ((lane >> 4) & 3) * 8;
    unsigned int pk[4];
#pragma unroll
    for (int jj = 0; jj < 4; ++jj)
      pk[jj] = f2bf(W2[(size_t)(k0 + 2 * jj) * 128 + n])
             | (f2bf(W2[(size_t)(k0 + 2 * jj + 1) * 128 + n]) << 16);
    *(uint4*)(W2p + (size_t)(((ntile * 4 + kstep) * 64 + lane) * 8)) =
        make_uint4(pk[0], pk[1], pk[2], pk[3]);
  }
}

// class-s blocks read ONLY segment s (12.8 MB total, coalesced); cursor atomics
// and col writes stay XCD-local under the blockIdx%8 round-robin.
__global__ __launch_bounds__(256) void fill_seg_kernel(const uint2* __restrict__ ebuf,
                                                       const int* __restrict__ clsCount,
                                                       int segCap, int* cursor,
                                                       int* __restrict__ col, int nq, int nr) {
  int sub = blockIdx.x & 7;
  int start = (blockIdx.x >> 3) * CHUNK;
  int count = clsCount[sub];
  const uint2* seg = ebuf + (size_t)sub * segCap;
#pragma unroll
  for (int j = 0; j < CHUNK / 256; ++j) {
    int e = start + j * 256 + threadIdx.x;
    if (e < count) {
      uint2 p = seg[e];
      int pos = atomicAdd(&cursor[rankof((int)p.x, nq, nr)], 1);
      col[pos] = (int)p.y;
    }
  }
}

// ---------------- layer 1 fused: xa = dinv_i * sum(xp), hA = bf16(dinv_i * relu(xa@W1+b1)) ----------------
// 128 nodes/block, 2 threads/node (even/odd edge interleave).

__global__ __launch_bounds__(256) void agg9_gemm1_kernel(const unsigned short* __restrict__ xp,
    const float* __restrict__ dinv, const int2* __restrict__ rows,
    const int* __restrict__ col, const float* __restrict__ W1,
    const float* __restrict__ b1, unsigned short* __restrict__ hA, int N) {
  __shared__ float sW[9 * 128];
  __shared__ float sx[128 * 9];
  __shared__ float sdi[128];           // per-row dinv for the GEMV-phase prescale
  int tid = threadIdx.x;
  for (int q = tid; q < 9 * 128; q += 256) sW[q] = W1[q];
  int nl = tid >> 1;                   // node-local 0..127
  int sl = tid & 1;                    // edge slot (even/odd)
  int i = blockIdx.x * 128 + nl;
  float A[9], B[9];
#pragma unroll
  for (int f = 0; f < 9; ++f) { A[f] = 0.0f; B[f] = 0.0f; }
  float di = 0.0f;
  if (i < N) {
    di = dinv[i];
    if (sl == 0) {                     // self term counted once
      const unsigned short* xi = xp + (size_t)i * 16;
      uint4 s0 = *(const uint4*)xi;
      unsigned int s1 = *(const unsigned int*)(xi + 8);
      A[0] = bflo(s0.x); A[1] = bfhi(s0.x); A[2] = bflo(s0.y); A[3] = bfhi(s0.y);
      A[4] = bflo(s0.z); A[5] = bfhi(s0.z); A[6] = bflo(s0.w); A[7] = bfhi(s0.w);
      A[8] = bflo(s1);
    }
    int2 rw = rows[i];
    int re = rw.y;
    int e = rw.x + sl;
    for (; e + 2 < re; e += 4) {       // this thread: edges e, e+2 (stride-2 split)
      int c0 = __builtin_nontemporal_load(&col[e]);
      int c1 = __builtin_nontemporal_load(&col[e + 2]);
      const unsigned short* p0 = xp + (size_t)c0 * 16;
      const unsigned short* p1 = xp + (size_t)c1 * 16;
      uint4 q0 = *(const uint4*)p0;
      unsigned int t0 = *(const unsigned int*)(p0 + 8);
      uint4 q1 = *(const uint4*)p1;
      unsigned int t1 = *(const unsigned int*)(p1 + 8);
      A[0] += bflo(q0.x); A[1] += bfhi(q0.x); A[2] += bflo(q0.y); A[3] += bfhi(q0.y);
      A[4] += bflo(q0.z); A[5] += bfhi(q0.z); A[6] += bflo(q0.w); A[7] += bfhi(q0.w);
      A[8] += bflo(t0);
      B[0] += bflo(q1.x); B[1] += bfhi(q1.x); B[2] += bflo(q1.y); B[3] += bfhi(q1.y);
      B[4] += bflo(q1.z); B[5] += bfhi(q1.z); B[6] += bflo(q1.w); B[7] += bfhi(q1.w);
      B[8] += bflo(t1);
    }
    for (; e < re; e += 2) {
      int c0 = __builtin_nontemporal_load(&col[e]);
      const unsigned short* p0 = xp + (size_t)c0 * 16;
      uint4 q0 = *(const uint4*)p0;
      unsigned int t0 = *(const unsigned int*)(p0 + 8);
      A[0] += bflo(q0.x); A[1] += bfhi(q0.x); A[2] += bflo(q0.y); A[3] += bfhi(q0.y);
      A[4] += bflo(q0.z); A[5] += bfhi(q0.z); A[6] += bflo(q0.w); A[7] += bfhi(q0.w);
      A[8] += bflo(t0);
    }
  }
  // combine the two per-node partials across lane-pair (same wave)
#pragma unroll
  for (int f = 0; f < 9; ++f) {
    float tsum = A[f] + B[f];
    tsum += __shfl_xor(tsum, 1, 64);
    A[f] = tsum;
  }
  if (sl == 0) {
    float* so = sx + nl * 9;           // stride 9: worst 2-way alias (free)
#pragma unroll
    for (int f = 0; f < 9; ++f) so[f] = A[f] * di;
    sdi[nl] = di;
  }
  __syncthreads();
  // GEMV phase: thread owns TWO adjacent output columns -> one packed 4B store.
  int c2i = tid & 63, rsub = tid >> 6;   // 64 col-pairs x 4 row-slots
  float wA[9], wB[9];
#pragma unroll
  for (int f = 0; f < 9; ++f) {
    wA[f] = sW[f * 128 + 2 * c2i];
    wB[f] = sW[f * 128 + 2 * c2i + 1];
  }
  float biasA = b1[2 * c2i], biasB = b1[2 * c2i + 1];
  int base = blockIdx.x * 128;
  for (int j = 0; j < 32; ++j) {
    int rl = j * 4 + rsub;             // wave-uniform -> sx reads broadcast
    int row = base + rl;
    if (row >= N) break;               // wave-uniform break
    float sA = biasA, sB = biasB;
#pragma unroll
    for (int f = 0; f < 9; ++f) {
      float xv = sx[rl * 9 + f];
      sA = fmaf(xv, wA[f], sA);
      sB = fmaf(xv, wB[f], sB);
    }
    float d = sdi[rl];
    unsigned int pk = f2bf(fmaxf(sA, 0.0f) * d) | (f2bf(fmaxf(sB, 0.0f) * d) << 16);
    *(unsigned int*)(hA + (size_t)row * 128 + 2 * c2i) = pk;
  }
}

// ---------------- layer 2 aggregation: S = (A+I)-sum of prescaled-h1 rows ----------------
// Half-wave: 32 lanes x uint2 (8B) = one full 256B bf16 row; 8 edges/iter.
// [r16-r18: ~72.5 us, FETCH = 8 XCD x 25.6 MB compulsory floor]

__global__ __launch_bounds__(256) void aggH_kernel(const unsigned short* __restrict__ h,
    const int2* __restrict__ rows, const int* __restrict__ col,
    unsigned short* __restrict__ g, int N) {
  int wave = threadIdx.x >> 6;
  int lane = threadIdx.x & 63;
  int half = lane >> 5;                // each 32-lane half gathers one full row
  int l32  = lane & 31;
  int i = blockIdx.x * 4 + wave;
  if (i >= N) return;                  // wave-uniform exit
  uint2 sp = *((const uint2*)(h + (size_t)i * 128) + l32);
  float m = half ? 0.0f : 1.0f;        // self counted once (lower half)
  float4 a0 = make_float4(bflo(sp.x) * m, bfhi(sp.x) * m, bflo(sp.y) * m, bfhi(sp.y) * m);
  float4 a1 = make_float4(0.f, 0.f, 0.f, 0.f);
  float4 a2 = make_float4(0.f, 0.f, 0.f, 0.f);
  float4 a3 = make_float4(0.f, 0.f, 0.f, 0.f);
  int2 rw = rows[i];
  int rs = rw.x, re = rw.y;
  int e = rs;
  for (; e + 8 <= re; e += 8) {        // 8 edges/iter, 4 gathers in flight per half
    int c0 = __builtin_nontemporal_load(&col[e + half]);
    int c1 = __builtin_nontemporal_load(&col[e + 2 + half]);
    int c2 = __builtin_nontemporal_load(&col[e + 4 + half]);
    int c3 = __builtin_nontemporal_load(&col[e + 6 + half]);
    uint2 p0 = *((const uint2*)(h + (size_t)c0 * 128) + l32);
    uint2 p1 = *((const uint2*)(h + (size_t)c1 * 128) + l32);
    uint2 p2 = *((const uint2*)(h + (size_t)c2 * 128) + l32);
    uint2 p3 = *((const uint2*)(h + (size_t)c3 * 128) + l32);
    a0.x += bflo(p0.x); a0.y += bfhi(p0.x); a0.z += bflo(p0.y); a0.w += bfhi(p0.y);
    a1.x += bflo(p1.x); a1.y += bfhi(p1.x); a1.z += bflo(p1.y); a1.w += bfhi(p1.y);
    a2.x += bflo(p2.x); a2.y += bfhi(p2.x); a2.z += bflo(p2.y); a2.w += bfhi(p2.y);
    a3.x += bflo(p3.x); a3.y += bfhi(p3.x); a3.z += bflo(p3.y); a3.w += bfhi(p3.y);
  }
  if (e + 4 <= re) {
    int c0 = __builtin_nontemporal_load(&col[e + half]);
    int c1 = __builtin_nontemporal_load(&col[e + 2 + half]);
    uint2 p0 = *((const uint2*)(h + (size_t)c0 * 128) + l32);
    uint2 p1 = *((const uint2*)(h + (size_t)c1 * 128) + l32);
    a0.x += bflo(p0.x); a0.y += bfhi(p0.x); a0.z += bflo(p0.y); a0.w += bfhi(p0.y);
    a1.x += bflo(p1.x); a1.y += bfhi(p1.x); a1.z += bflo(p1.y); a1.w += bfhi(p1.y);
    e += 4;
  }
  if (e + 2 <= re) {
    int c0 = __builtin_nontemporal_load(&col[e + half]);
    uint2 p0 = *((const uint2*)(h + (size_t)c0 * 128) + l32);
    a2.x += bflo(p0.x); a2.y += bfhi(p0.x); a2.z += bflo(p0.y); a2.w += bfhi(p0.y);
    e += 2;
  }
  if (e < re) {                        // odd tail: both halves take 0.5 (exact)
    int c0 = __builtin_nontemporal_load(&col[e]);
    uint2 p0 = *((const uint2*)(h + (size_t)c0 * 128) + l32);
    a3.x = fmaf(bflo(p0.x), 0.5f, a3.x); a3.y = fmaf(bfhi(p0.x), 0.5f, a3.y);
    a3.z = fmaf(bflo(p0.y), 0.5f, a3.z); a3.w = fmaf(bfhi(p0.y), 0.5f, a3.w);
  }
  float4 a = make_float4((a0.x + a1.x) + (a2.x + a3.x), (a0.y + a1.y) + (a2.y + a3.y),
                         (a0.z + a1.z) + (a2.z + a3.z), (a0.w + a1.w) + (a2.w + a3.w));
  a.x += __shfl_down(a.x, 32, 64);     // combine halves -> lanes 0..31 hold full row
  a.y += __shfl_down(a.y, 32, 64);
  a.z += __shfl_down(a.z, 32, 64);
  a.w += __shfl_down(a.w, 32, 64);
  if (half == 0) {                     // lanes 0..31 pack bf16 -> 256B row store
    uint2 o;
    o.x = f2bf(a.x) | (f2bf(a.y) << 16);
    o.y = f2bf(a.z) | (f2bf(a.w) << 16);
    *((uint2*)(g + (size_t)i * 128) + l32) = o;
  }
}

// ---------------- fused layer-2/3 head via bf16 MFMA ----------------
// zd = dinv .* (relu(dinv.*(S@W2) + b2) @ v). LDS-free, barrier-free.

__global__ __launch_bounds__(256) void gemmz_kernel(const unsigned short* __restrict__ g,
    const unsigned short* __restrict__ W2p, const float* __restrict__ dinv,
    const float* __restrict__ b2, const float* __restrict__ v,
    float* __restrict__ zd, int N) {
  int wave = threadIdx.x >> 6, lane = threadIdx.x & 63;
  int rb16 = blockIdx.x * 64 + wave * 16;       // wave's 16-row window
  int m = lane & 15, quad = lane >> 4;
  int rowA = rb16 + m;
  const unsigned short* gp = g + (size_t)((rowA < N) ? rowA : N) * 128 + quad * 8;
  floatx4 acc[8];
#pragma unroll
  for (int t = 0; t < 8; ++t) acc[t] = (floatx4){0.f, 0.f, 0.f, 0.f};
#pragma unroll
  for (int ks = 0; ks < 4; ++ks) {
    short8 afrag = *(const short8*)(gp + ks * 32);
#pragma unroll
    for (int t = 0; t < 8; ++t) {
      short8 bfrag = *(const short8*)(W2p + (size_t)(((t * 4 + ks) * 64 + lane) * 8));
      acc[t] = __builtin_amdgcn_mfma_f32_16x16x32_bf16(afrag, bfrag, acc[t], 0, 0, 0);
    }
  }
  float b2c[8], vc[8];
#pragma unroll
  for (int t = 0; t < 8; ++t) {
    int ncol = t * 16 + m;
    b2c[t] = b2[ncol];
    vc[t] = v[ncol];
  }
#pragma unroll
  for (int reg = 0; reg < 4; ++reg) {
    int grow = rb16 + quad * 4 + reg;
    float dr = (grow < N) ? dinv[grow] : 0.0f;
    float p = 0.0f;
#pragma unroll
    for (int t = 0; t < 8; ++t)
      p += fmaxf(fmaf(dr, acc[t][reg], b2c[t]), 0.0f) * vc[t];
#pragma unroll
    for (int mk = 1; mk <= 8; mk <<= 1) p += __shfl_xor(p, mk, 64);  // over m (lane&15)
    if (m == 0 && grow < N) zd[grow] = dr * p;   // prescaled for layer-3
  }
}

// ---------------- layer 3 (scalar) aggregation + mean-pool binning ----------------
// 128 nodes/block, 2 threads/node (even/odd edges).

__global__ void agg1_pool_kernel(const float* __restrict__ zd, const float* __restrict__ dinv,
    const int2* __restrict__ rows, const int* __restrict__ col,
    const int* __restrict__ batch, float* gsum, float* gcnt, int N) {
  __shared__ float lsum[64];
  __shared__ float lcnt[64];
  int t = threadIdx.x;
  if (t < 64) { lsum[t] = 0.0f; lcnt[t] = 0.0f; }
  __syncthreads();
  int nl = t >> 1, sl = t & 1;
  int i = blockIdx.x * 128 + nl;
  float acc = 0.0f;
  if (i < N) {
    int2 rw = rows[i];
    int re = rw.y;
    if (sl == 0) acc = zd[i];          // self (weight 1 in prescaled domain)
    int e = rw.x + sl;
    for (; e + 2 < re; e += 4) {       // this thread: edges e, e+2
      float z0 = zd[col[e]], z1 = zd[col[e + 2]];
      acc += z0 + z1;
    }
    for (; e < re; e += 2) acc += zd[col[e]];
  }
  acc += __shfl_xor(acc, 1, 64);       // combine lane pair
  if (i < N && sl == 0) {
    acc *= dinv[i];
    int gidx = batch[i];
    atomicAdd(&lsum[gidx], acc);
    atomicAdd(&lcnt[gidx], 1.0f);
  }
  __syncthreads();
  if (t < 64) {
    if (lsum[t] != 0.0f) atomicAdd(&gsum[t], lsum[t]);
    if (lcnt[t] != 0.0f) atomicAdd(&gcnt[t], lcnt[t]);
  }
}

__global__ void final_kernel(const float* __restrict__ gsum, const float* __restrict__ gcnt,
                             const float* __restrict__ c0, float* out, int G) {
  int g = threadIdx.x;
  if (g < G) out[g] = gsum[g] / fmaxf(gcnt[g], 1.0f) + c0[0];
}

// ---------------- launch ----------------

extern "C" void kernel_launch(void* const* d_in, const int* in_sizes, int n_in,
                              void* d_out, int out_size, void* d_ws, size_t ws_size,
                              hipStream_t stream) {
  const float* x      = (const float*)d_in[0];
  const int*   eidx   = (const int*)d_in[1];
  const int*   batch  = (const int*)d_in[2];
  const float* W1     = (const float*)d_in[3];
  const float* b1     = (const float*)d_in[4];
  const float* W2     = (const float*)d_in[5];
  const float* b2     = (const float*)d_in[6];
  const float* W3     = (const float*)d_in[7];
  const float* b3     = (const float*)d_in[8];
  const float* lin_w  = (const float*)d_in[9];
  const float* lin_b  = (const float*)d_in[10];
  float* out = (float*)d_out;

  int N = in_sizes[0] / 9;
  int E = in_sizes[1] / 2;
  int G = out_size;
  const int* src = eidx;
  const int* dst = eidx + E;
  int nq = N >> 3, nr = N & 7;         // rank(i) = (i&7)*nq + min(i&7,nr) + (i>>3)

  char* w = (char*)d_ws;
  size_t off = 0;
  auto alloc = [&](size_t bytes) -> void* {
    void* p = w + off;
    off += bytes;
    off = (off + 255) & ~(size_t)255;
    return p;
  };

  int nb = (N + 255) / 256;
  int nb2 = (N + 127) / 128;
  int nchunk = (E + CHUNK - 1) / CHUNK;
  int segCap = E / 8 + 65536;          // per-class segment capacity (33+ sigma slack)
  int nseg = (segCap + CHUNK - 1) / CHUNK;
  // zero-init region (one memset): cursor (rank-space degree counts), gsum, gcnt, clsCount
  int*   cursor   = (int*)  alloc((size_t)N * 4);      // counts, then fill cursor (rank-indexed)
  float* gsum     = (float*)alloc(64 * 4);
  float* gcnt     = (float*)alloc(64 * 4);
  int*   clsCount = (int*)  alloc(8 * 4);
  size_t zspan = off;
  float* dinv   = (float*)alloc((size_t)N * 4);
  int2*  rows   = (int2*) alloc((size_t)N * 8);        // node-indexed (rs,re)
  int*   bsum   = (int*)  alloc((size_t)nb * 4);
  int*   colsrc = (int*)  alloc((size_t)E * 4);        // CSR cols, class-contiguous regions
  uint2* ebuf   = (uint2*)alloc((size_t)segCap * 8 * 8);  // class-bucketed (dst,src)
  unsigned short* hA  = (unsigned short*)alloc((size_t)N * 128 * 2);        // prescaled h1, BF16
  unsigned short* g   = (unsigned short*)alloc((size_t)(N + 1) * 128 * 2);  // xp (Nx16 bf16) first, then S BF16 (+pad row N)
  unsigned short* W2p = (unsigned short*)alloc(8 * 4 * 64 * 8 * 2);         // MFMA B-frag packed W2
  float* zd     = (float*)alloc((size_t)N * 4);
  float* v      = (float*)alloc(128 * 4);
  float* c0     = (float*)alloc(4);
  unsigned short* xp = g;                              // alias: dead before aggH writes g

  hipMemsetAsync(d_ws, 0, zspan, stream);
  bucket_kernel<<<nchunk, 256, 0, stream>>>(src, dst, cursor, clsCount, ebuf, segCap, E, nq, nr);
  dinv_bsum_pad_kernel<<<nb, 256, 0, stream>>>(cursor, dinv, bsum, x, xp, N, nq, nr);
  rowptr_vc0_kernel<<<nb, 256, 0, stream>>>(cursor, bsum, rows, cursor, N, E, nq, nr,
                                            W3, b3, lin_w, lin_b, W2, W2p, g, v, c0);
  fill_seg_kernel<<<nseg * 8, 256, 0, stream>>>(ebuf, clsCount, segCap, cursor, colsrc, nq, nr);
  agg9_gemm1_kernel<<<nb2, 256, 0, stream>>>(xp, dinv, rows, colsrc, W1, b1, hA, N);
  aggH_kernel<<<(N + 3) / 4, 256, 0, stream>>>(hA, rows, colsrc, g, N);
  gemmz_kernel<<<(N + 63) / 64, 256, 0, stream>>>(g, W2p, dinv, b2, v, zd, N);
  agg1_pool_kernel<<<nb2, 256, 0, stream>>>(zd, dinv, rows, colsrc, batch, gsum, gcnt, N);
  final_kernel<<<1, 64, 0, stream>>>(gsum, gcnt, c0, out, G);
}

// Round 20
// 364.727 us; speedup vs baseline: 1.0325x; 1.0325x over previous
//
#include <hip/hip_runtime.h>
#include <math.h>

// Factorized GCN: A_hat = D^-1/2 (A+I) D^-1/2. All aggregations are
// prescale(rows by dinv) -> pure gather-sum over CSR cols -> postscale by dinv.
// CSR rows RANK-PERMUTED by class c=i&7 (fill's col lines owned by one XCD);
// node-indexed rows[i]=(rs,re). BF16 storage everywhere it's gathered/streamed:
// xp (prescaled x, 32B rows), hA (prescaled h1), g (aggregated S). fp32 acc.
// gemmz via bf16 MFMA (W2 pre-packed B-frags). aggH half-wave (r15/16 lesson).
// r19's bucketed CSR build regressed (302k LDS same-address atomic conflicts,
// 62MB scattered-append write-amp) — reverted to deg + dst&7-partitioned fill.
// This is the r18 configuration: 362.2 us measured, absmax 7.6e-6.

#define CHUNK 2048

using short8 = __attribute__((ext_vector_type(8))) short;
using floatx4 = __attribute__((ext_vector_type(4))) float;

__device__ __forceinline__ int rankof(int i, int nq, int nr) {
  int c = i & 7;
  return c * nq + min(c, nr) + (i >> 3);
}
__device__ __forceinline__ unsigned int f2bf(float f) {   // RNE
  unsigned int u = __float_as_uint(f);
  return ((u + 0x7fff + ((u >> 16) & 1)) >> 16);
}
__device__ __forceinline__ float bflo(unsigned int u) { return __uint_as_float(u << 16); }
__device__ __forceinline__ float bfhi(unsigned int u) { return __uint_as_float(u & 0xffff0000u); }

// ---------------- setup kernels ----------------

__global__ void deg_kernel(const int* __restrict__ dst, int* cnt_rank,
                           int E, int nq, int nr) {
  int e = blockIdx.x * blockDim.x + threadIdx.x;
  if (e < E) atomicAdd(&cnt_rank[rankof(dst[e], nq, nr)], 1);
}

// dinv + per-block rank-order sums -> bsum; xp = bf16(dinv_i * x_i), 16 bf16/row (32B)
__global__ void dinv_bsum_pad_kernel(const int* __restrict__ cnt_rank,
                                     float* __restrict__ dinv, int* bsum,
                                     const float* __restrict__ x,
                                     unsigned short* __restrict__ xp, int N, int nq, int nr) {
  __shared__ int s[256];
  int t = threadIdx.x;
  int gid = blockIdx.x * 256 + t;
  s[t] = (gid < N) ? cnt_rank[gid] : 0;     // scan basis: rank-order, coalesced
  if (gid < N) {
    int c = cnt_rank[rankof(gid, nq, nr)];  // this node's in-degree
    float di = 1.0f / sqrtf((float)c + 1.0f);
    dinv[gid] = di;
    const float* xr = x + (size_t)gid * 9;
    unsigned int w0 = f2bf(xr[0] * di) | (f2bf(xr[1] * di) << 16);
    unsigned int w1 = f2bf(xr[2] * di) | (f2bf(xr[3] * di) << 16);
    unsigned int w2 = f2bf(xr[4] * di) | (f2bf(xr[5] * di) << 16);
    unsigned int w3 = f2bf(xr[6] * di) | (f2bf(xr[7] * di) << 16);
    unsigned int w4 = f2bf(xr[8] * di);
    uint4* xo = (uint4*)(xp + (size_t)gid * 16);
    xo[0] = make_uint4(w0, w1, w2, w3);
    xo[1] = make_uint4(w4, 0u, 0u, 0u);
  }
  __syncthreads();
  for (int off = 128; off > 0; off >>= 1) {
    if (t < off) s[t] += s[t + off];
    __syncthreads();
  }
  if (t == 0) bsum[blockIdx.x] = s[0];
}

// Scan over RANK space -> rank-indexed cursor (fill) + NODE-indexed rows[i].
// Block 0: v = W3@lin_w, c0 = b3.lin_w + lin_b; zero g row N (gemmz pad row).
// Blocks 1..8: pack W2 -> bf16 B-fragment layout W2p[ntile][kstep][lane][8].
__global__ void rowptr_vc0_kernel(const int* __restrict__ indeg, const int* __restrict__ bsum,
                                  int2* __restrict__ rows, int* cursor, int N, int E,
                                  int nq, int nr,
                                  const float* __restrict__ W3, const float* __restrict__ b3,
                                  const float* __restrict__ lin_w, const float* __restrict__ lin_b,
                                  const float* __restrict__ W2, unsigned short* __restrict__ W2p,
                                  unsigned short* __restrict__ g,
                                  float* v, float* c0) {
  __shared__ int ps[256];
  __shared__ int s[256];
  int t = threadIdx.x;
  int pref = 0;
  for (int q = t; q < blockIdx.x; q += 256) pref += bsum[q];
  ps[t] = pref;
  __syncthreads();
  for (int off = 128; off > 0; off >>= 1) {
    if (t < off) ps[t] += ps[t + off];
    __syncthreads();
  }
  int base = ps[0];
  int r = blockIdx.x * 256 + t;
  int val = (r < N) ? indeg[r] : 0;
  s[t] = val;
  __syncthreads();
  for (int off = 1; off < 256; off <<= 1) {
    int x = (t >= off) ? s[t - off] : 0;
    __syncthreads();
    s[t] += x;
    __syncthreads();
  }
  int excl = s[t] - val + base;
  if (r < N) {
    cursor[r] = excl;                       // rank-indexed fill cursor
    int c = 0;                              // invert rank -> node id
#pragma unroll
    for (int cc = 1; cc < 8; ++cc) {
      int b = cc * nq + min(cc, nr);
      if (r >= b) c = cc;
    }
    int iinv = ((r - (c * nq + min(c, nr))) << 3) | c;
    rows[iinv] = make_int2(excl, excl + val);  // node-indexed (scattered, once)
  }
  if (blockIdx.x == 0) {
    if (t < 64) ((unsigned int*)g)[(size_t)N * 64 + t] = 0u;  // zero pad row N
    if (t < 128) {
      float sv = 0.0f;
      for (int c = 0; c < 128; ++c) sv = fmaf(W3[t * 128 + c], lin_w[c], sv);
      v[t] = sv;
    } else if (t == 128) {
      float sv = 0.0f;
      for (int c = 0; c < 128; ++c) sv = fmaf(b3[c], lin_w[c], sv);
      c0[0] = sv + lin_b[0];
    }
  } else if (blockIdx.x <= 8) {
    // B-frag pack: lane holds W2[k][n], n = ntile*16 + (lane&15),
    // k = kstep*32 + (lane>>4)*8 + j, j=0..7
    int ntile = blockIdx.x - 1;
    int kstep = t >> 6, lane = t & 63;
    int n = ntile * 16 + (lane & 15);
    int k0 = kstep * 32 + ((lane >> 4) & 3) * 8;
    unsigned int pk[4];
#pragma unroll
    for (int jj = 0; jj < 4; ++jj)
      pk[jj] = f2bf(W2[(size_t)(k0 + 2 * jj) * 128 + n])
             | (f2bf(W2[(size_t)(k0 + 2 * jj + 1) * 128 + n]) << 16);
    *(uint4*)(W2p + (size_t)(((ntile * 4 + kstep) * 64 + lane) * 8)) =
        make_uint4(pk[0], pk[1], pk[2], pk[3]);
  }
}

__global__ __launch_bounds__(256) void fill_part_kernel(const int* __restrict__ src,
                                                        const int* __restrict__ dst,
                                                        int* cursor, int* __restrict__ col,
                                                        int E, int nq, int nr) {
  int sub = blockIdx.x & 7;
  int base = (blockIdx.x >> 3) * CHUNK;
#pragma unroll
  for (int j = 0; j < CHUNK / 256; ++j) {
    int e = base + j * 256 + threadIdx.x;
    if (e < E) {
      int d = dst[e];
      if ((d & 7) == sub) {
        int p = atomicAdd(&cursor[rankof(d, nq, nr)], 1);
        col[p] = src[e];
      }
    }
  }
}

// ---------------- layer 1 fused: xa = dinv_i * sum(xp), hA = bf16(dinv_i * relu(xa@W1+b1)) ----------------
// 128 nodes/block, 2 threads/node (even/odd edge interleave).

__global__ __launch_bounds__(256) void agg9_gemm1_kernel(const unsigned short* __restrict__ xp,
    const float* __restrict__ dinv, const int2* __restrict__ rows,
    const int* __restrict__ col, const float* __restrict__ W1,
    const float* __restrict__ b1, unsigned short* __restrict__ hA, int N) {
  __shared__ float sW[9 * 128];
  __shared__ float sx[128 * 9];
  __shared__ float sdi[128];           // per-row dinv for the GEMV-phase prescale
  int tid = threadIdx.x;
  for (int q = tid; q < 9 * 128; q += 256) sW[q] = W1[q];
  int nl = tid >> 1;                   // node-local 0..127
  int sl = tid & 1;                    // edge slot (even/odd)
  int i = blockIdx.x * 128 + nl;
  float A[9], B[9];
#pragma unroll
  for (int f = 0; f < 9; ++f) { A[f] = 0.0f; B[f] = 0.0f; }
  float di = 0.0f;
  if (i < N) {
    di = dinv[i];
    if (sl == 0) {                     // self term counted once
      const unsigned short* xi = xp + (size_t)i * 16;
      uint4 s0 = *(const uint4*)xi;
      unsigned int s1 = *(const unsigned int*)(xi + 8);
      A[0] = bflo(s0.x); A[1] = bfhi(s0.x); A[2] = bflo(s0.y); A[3] = bfhi(s0.y);
      A[4] = bflo(s0.z); A[5] = bfhi(s0.z); A[6] = bflo(s0.w); A[7] = bfhi(s0.w);
      A[8] = bflo(s1);
    }
    int2 rw = rows[i];
    int re = rw.y;
    int e = rw.x + sl;
    for (; e + 2 < re; e += 4) {       // this thread: edges e, e+2 (stride-2 split)
      int c0 = __builtin_nontemporal_load(&col[e]);
      int c1 = __builtin_nontemporal_load(&col[e + 2]);
      const unsigned short* p0 = xp + (size_t)c0 * 16;
      const unsigned short* p1 = xp + (size_t)c1 * 16;
      uint4 q0 = *(const uint4*)p0;
      unsigned int t0 = *(const unsigned int*)(p0 + 8);
      uint4 q1 = *(const uint4*)p1;
      unsigned int t1 = *(const unsigned int*)(p1 + 8);
      A[0] += bflo(q0.x); A[1] += bfhi(q0.x); A[2] += bflo(q0.y); A[3] += bfhi(q0.y);
      A[4] += bflo(q0.z); A[5] += bfhi(q0.z); A[6] += bflo(q0.w); A[7] += bfhi(q0.w);
      A[8] += bflo(t0);
      B[0] += bflo(q1.x); B[1] += bfhi(q1.x); B[2] += bflo(q1.y); B[3] += bfhi(q1.y);
      B[4] += bflo(q1.z); B[5] += bfhi(q1.z); B[6] += bflo(q1.w); B[7] += bfhi(q1.w);
      B[8] += bflo(t1);
    }
    for (; e < re; e += 2) {
      int c0 = __builtin_nontemporal_load(&col[e]);
      const unsigned short* p0 = xp + (size_t)c0 * 16;
      uint4 q0 = *(const uint4*)p0;
      unsigned int t0 = *(const unsigned int*)(p0 + 8);
      A[0] += bflo(q0.x); A[1] += bfhi(q0.x); A[2] += bflo(q0.y); A[3] += bfhi(q0.y);
      A[4] += bflo(q0.z); A[5] += bfhi(q0.z); A[6] += bflo(q0.w); A[7] += bfhi(q0.w);
      A[8] += bflo(t0);
    }
  }
  // combine the two per-node partials across lane-pair (same wave)
#pragma unroll
  for (int f = 0; f < 9; ++f) {
    float tsum = A[f] + B[f];
    tsum += __shfl_xor(tsum, 1, 64);
    A[f] = tsum;
  }
  if (sl == 0) {
    float* so = sx + nl * 9;           // stride 9: worst 2-way alias (free)
#pragma unroll
    for (int f = 0; f < 9; ++f) so[f] = A[f] * di;
    sdi[nl] = di;
  }
  __syncthreads();
  // GEMV phase: thread owns TWO adjacent output columns -> one packed 4B store.
  int c2i = tid & 63, rsub = tid >> 6;   // 64 col-pairs x 4 row-slots
  float wA[9], wB[9];
#pragma unroll
  for (int f = 0; f < 9; ++f) {
    wA[f] = sW[f * 128 + 2 * c2i];
    wB[f] = sW[f * 128 + 2 * c2i + 1];
  }
  float biasA = b1[2 * c2i], biasB = b1[2 * c2i + 1];
  int base = blockIdx.x * 128;
  for (int j = 0; j < 32; ++j) {
    int rl = j * 4 + rsub;             // wave-uniform -> sx reads broadcast
    int row = base + rl;
    if (row >= N) break;               // wave-uniform break
    float sA = biasA, sB = biasB;
#pragma unroll
    for (int f = 0; f < 9; ++f) {
      float xv = sx[rl * 9 + f];
      sA = fmaf(xv, wA[f], sA);
      sB = fmaf(xv, wB[f], sB);
    }
    float d = sdi[rl];
    unsigned int pk = f2bf(fmaxf(sA, 0.0f) * d) | (f2bf(fmaxf(sB, 0.0f) * d) << 16);
    *(unsigned int*)(hA + (size_t)row * 128 + 2 * c2i) = pk;
  }
}

// ---------------- layer 2 aggregation: S = (A+I)-sum of prescaled-h1 rows ----------------
// Half-wave: 32 lanes x uint2 (8B) = one full 256B bf16 row; 8 edges/iter.
// [r16-r18: ~72.5 us, FETCH = 8 XCD x 25.6 MB compulsory floor]

__global__ __launch_bounds__(256) void aggH_kernel(const unsigned short* __restrict__ h,
    const int2* __restrict__ rows, const int* __restrict__ col,
    unsigned short* __restrict__ g, int N) {
  int wave = threadIdx.x >> 6;
  int lane = threadIdx.x & 63;
  int half = lane >> 5;                // each 32-lane half gathers one full row
  int l32  = lane & 31;
  int i = blockIdx.x * 4 + wave;
  if (i >= N) return;                  // wave-uniform exit
  uint2 sp = *((const uint2*)(h + (size_t)i * 128) + l32);
  float m = half ? 0.0f : 1.0f;        // self counted once (lower half)
  float4 a0 = make_float4(bflo(sp.x) * m, bfhi(sp.x) * m, bflo(sp.y) * m, bfhi(sp.y) * m);
  float4 a1 = make_float4(0.f, 0.f, 0.f, 0.f);
  float4 a2 = make_float4(0.f, 0.f, 0.f, 0.f);
  float4 a3 = make_float4(0.f, 0.f, 0.f, 0.f);
  int2 rw = rows[i];
  int rs = rw.x, re = rw.y;
  int e = rs;
  for (; e + 8 <= re; e += 8) {        // 8 edges/iter, 4 gathers in flight per half
    int c0 = __builtin_nontemporal_load(&col[e + half]);
    int c1 = __builtin_nontemporal_load(&col[e + 2 + half]);
    int c2 = __builtin_nontemporal_load(&col[e + 4 + half]);
    int c3 = __builtin_nontemporal_load(&col[e + 6 + half]);
    uint2 p0 = *((const uint2*)(h + (size_t)c0 * 128) + l32);
    uint2 p1 = *((const uint2*)(h + (size_t)c1 * 128) + l32);
    uint2 p2 = *((const uint2*)(h + (size_t)c2 * 128) + l32);
    uint2 p3 = *((const uint2*)(h + (size_t)c3 * 128) + l32);
    a0.x += bflo(p0.x); a0.y += bfhi(p0.x); a0.z += bflo(p0.y); a0.w += bfhi(p0.y);
    a1.x += bflo(p1.x); a1.y += bfhi(p1.x); a1.z += bflo(p1.y); a1.w += bfhi(p1.y);
    a2.x += bflo(p2.x); a2.y += bfhi(p2.x); a2.z += bflo(p2.y); a2.w += bfhi(p2.y);
    a3.x += bflo(p3.x); a3.y += bfhi(p3.x); a3.z += bflo(p3.y); a3.w += bfhi(p3.y);
  }
  if (e + 4 <= re) {
    int c0 = __builtin_nontemporal_load(&col[e + half]);
    int c1 = __builtin_nontemporal_load(&col[e + 2 + half]);
    uint2 p0 = *((const uint2*)(h + (size_t)c0 * 128) + l32);
    uint2 p1 = *((const uint2*)(h + (size_t)c1 * 128) + l32);
    a0.x += bflo(p0.x); a0.y += bfhi(p0.x); a0.z += bflo(p0.y); a0.w += bfhi(p0.y);
    a1.x += bflo(p1.x); a1.y += bfhi(p1.x); a1.z += bflo(p1.y); a1.w += bfhi(p1.y);
    e += 4;
  }
  if (e + 2 <= re) {
    int c0 = __builtin_nontemporal_load(&col[e + half]);
    uint2 p0 = *((const uint2*)(h + (size_t)c0 * 128) + l32);
    a2.x += bflo(p0.x); a2.y += bfhi(p0.x); a2.z += bflo(p0.y); a2.w += bfhi(p0.y);
    e += 2;
  }
  if (e < re) {                        // odd tail: both halves take 0.5 (exact)
    int c0 = __builtin_nontemporal_load(&col[e]);
    uint2 p0 = *((const uint2*)(h + (size_t)c0 * 128) + l32);
    a3.x = fmaf(bflo(p0.x), 0.5f, a3.x); a3.y = fmaf(bfhi(p0.x), 0.5f, a3.y);
    a3.z = fmaf(bflo(p0.y), 0.5f, a3.z); a3.w = fmaf(bfhi(p0.y), 0.5f, a3.w);
  }
  float4 a = make_float4((a0.x + a1.x) + (a2.x + a3.x), (a0.y + a1.y) + (a2.y + a3.y),
                         (a0.z + a1.z) + (a2.z + a3.z), (a0.w + a1.w) + (a2.w + a3.w));
  a.x += __shfl_down(a.x, 32, 64);     // combine halves -> lanes 0..31 hold full row
  a.y += __shfl_down(a.y, 32, 64);
  a.z += __shfl_down(a.z, 32, 64);
  a.w += __shfl_down(a.w, 32, 64);
  if (half == 0) {                     // lanes 0..31 pack bf16 -> 256B row store
    uint2 o;
    o.x = f2bf(a.x) | (f2bf(a.y) << 16);
    o.y = f2bf(a.z) | (f2bf(a.w) << 16);
    *((uint2*)(g + (size_t)i * 128) + l32) = o;
  }
}

// ---------------- fused layer-2/3 head via bf16 MFMA ----------------
// zd = dinv .* (relu(dinv.*(S@W2) + b2) @ v). LDS-free, barrier-free.

__global__ __launch_bounds__(256) void gemmz_kernel(const unsigned short* __restrict__ g,
    const unsigned short* __restrict__ W2p, const float* __restrict__ dinv,
    const float* __restrict__ b2, const float* __restrict__ v,
    float* __restrict__ zd, int N) {
  int wave = threadIdx.x >> 6, lane = threadIdx.x & 63;
  int rb16 = blockIdx.x * 64 + wave * 16;       // wave's 16-row window
  int m = lane & 15, quad = lane >> 4;
  int rowA = rb16 + m;
  const unsigned short* gp = g + (size_t)((rowA < N) ? rowA : N) * 128 + quad * 8;
  floatx4 acc[8];
#pragma unroll
  for (int t = 0; t < 8; ++t) acc[t] = (floatx4){0.f, 0.f, 0.f, 0.f};
#pragma unroll
  for (int ks = 0; ks < 4; ++ks) {
    short8 afrag = *(const short8*)(gp + ks * 32);
#pragma unroll
    for (int t = 0; t < 8; ++t) {
      short8 bfrag = *(const short8*)(W2p + (size_t)(((t * 4 + ks) * 64 + lane) * 8));
      acc[t] = __builtin_amdgcn_mfma_f32_16x16x32_bf16(afrag, bfrag, acc[t], 0, 0, 0);
    }
  }
  float b2c[8], vc[8];
#pragma unroll
  for (int t = 0; t < 8; ++t) {
    int ncol = t * 16 + m;
    b2c[t] = b2[ncol];
    vc[t] = v[ncol];
  }
#pragma unroll
  for (int reg = 0; reg < 4; ++reg) {
    int grow = rb16 + quad * 4 + reg;
    float dr = (grow < N) ? dinv[grow] : 0.0f;
    float p = 0.0f;
#pragma unroll
    for (int t = 0; t < 8; ++t)
      p += fmaxf(fmaf(dr, acc[t][reg], b2c[t]), 0.0f) * vc[t];
#pragma unroll
    for (int mk = 1; mk <= 8; mk <<= 1) p += __shfl_xor(p, mk, 64);  // over m (lane&15)
    if (m == 0 && grow < N) zd[grow] = dr * p;   // prescaled for layer-3
  }
}

// ---------------- layer 3 (scalar) aggregation + mean-pool binning ----------------
// 128 nodes/block, 2 threads/node (even/odd edges).

__global__ void agg1_pool_kernel(const float* __restrict__ zd, const float* __restrict__ dinv,
    const int2* __restrict__ rows, const int* __restrict__ col,
    const int* __restrict__ batch, float* gsum, float* gcnt, int N) {
  __shared__ float lsum[64];
  __shared__ float lcnt[64];
  int t = threadIdx.x;
  if (t < 64) { lsum[t] = 0.0f; lcnt[t] = 0.0f; }
  __syncthreads();
  int nl = t >> 1, sl = t & 1;
  int i = blockIdx.x * 128 + nl;
  float acc = 0.0f;
  if (i < N) {
    int2 rw = rows[i];
    int re = rw.y;
    if (sl == 0) acc = zd[i];          // self (weight 1 in prescaled domain)
    int e = rw.x + sl;
    for (; e + 2 < re; e += 4) {       // this thread: edges e, e+2
      float z0 = zd[col[e]], z1 = zd[col[e + 2]];
      acc += z0 + z1;
    }
    for (; e < re; e += 2) acc += zd[col[e]];
  }
  acc += __shfl_xor(acc, 1, 64);       // combine lane pair
  if (i < N && sl == 0) {
    acc *= dinv[i];
    int gidx = batch[i];
    atomicAdd(&lsum[gidx], acc);
    atomicAdd(&lcnt[gidx], 1.0f);
  }
  __syncthreads();
  if (t < 64) {
    if (lsum[t] != 0.0f) atomicAdd(&gsum[t], lsum[t]);
    if (lcnt[t] != 0.0f) atomicAdd(&gcnt[t], lcnt[t]);
  }
}

__global__ void final_kernel(const float* __restrict__ gsum, const float* __restrict__ gcnt,
                             const float* __restrict__ c0, float* out, int G) {
  int g = threadIdx.x;
  if (g < G) out[g] = gsum[g] / fmaxf(gcnt[g], 1.0f) + c0[0];
}

// ---------------- launch ----------------

extern "C" void kernel_launch(void* const* d_in, const int* in_sizes, int n_in,
                              void* d_out, int out_size, void* d_ws, size_t ws_size,
                              hipStream_t stream) {
  const float* x      = (const float*)d_in[0];
  const int*   eidx   = (const int*)d_in[1];
  const int*   batch  = (const int*)d_in[2];
  const float* W1     = (const float*)d_in[3];
  const float* b1     = (const float*)d_in[4];
  const float* W2     = (const float*)d_in[5];
  const float* b2     = (const float*)d_in[6];
  const float* W3     = (const float*)d_in[7];
  const float* b3     = (const float*)d_in[8];
  const float* lin_w  = (const float*)d_in[9];
  const float* lin_b  = (const float*)d_in[10];
  float* out = (float*)d_out;

  int N = in_sizes[0] / 9;
  int E = in_sizes[1] / 2;
  int G = out_size;
  const int* src = eidx;
  const int* dst = eidx + E;
  int nq = N >> 3, nr = N & 7;         // rank(i) = (i&7)*nq + min(i&7,nr) + (i>>3)

  char* w = (char*)d_ws;
  size_t off = 0;
  auto alloc = [&](size_t bytes) -> void* {
    void* p = w + off;
    off += bytes;
    off = (off + 255) & ~(size_t)255;
    return p;
  };

  int nb = (N + 255) / 256;
  int nb2 = (N + 127) / 128;
  int nchunk = (E + CHUNK - 1) / CHUNK;
  // zero-init region (one memset): cursor (rank-space degree counts), gsum, gcnt
  int*   cursor = (int*)  alloc((size_t)N * 4);        // counts, then fill cursor (rank-indexed)
  float* gsum   = (float*)alloc(64 * 4);
  float* gcnt   = (float*)alloc(64 * 4);
  size_t zspan = off;
  float* dinv   = (float*)alloc((size_t)N * 4);
  int2*  rows   = (int2*) alloc((size_t)N * 8);        // node-indexed (rs,re)
  int*   bsum   = (int*)  alloc((size_t)nb * 4);
  int*   colsrc = (int*)  alloc((size_t)E * 4);        // CSR cols, class-contiguous regions
  unsigned short* hA  = (unsigned short*)alloc((size_t)N * 128 * 2);        // prescaled h1, BF16
  unsigned short* g   = (unsigned short*)alloc((size_t)(N + 1) * 128 * 2);  // xp (Nx16 bf16) first, then S BF16 (+pad row N)
  unsigned short* W2p = (unsigned short*)alloc(8 * 4 * 64 * 8 * 2);         // MFMA B-frag packed W2
  float* zd     = (float*)alloc((size_t)N * 4);
  float* v      = (float*)alloc(128 * 4);
  float* c0     = (float*)alloc(4);
  unsigned short* xp = g;                              // alias: dead before aggH writes g

  hipMemsetAsync(d_ws, 0, zspan, stream);
  deg_kernel<<<(E + 255) / 256, 256, 0, stream>>>(dst, cursor, E, nq, nr);
  dinv_bsum_pad_kernel<<<nb, 256, 0, stream>>>(cursor, dinv, bsum, x, xp, N, nq, nr);
  rowptr_vc0_kernel<<<nb, 256, 0, stream>>>(cursor, bsum, rows, cursor, N, E, nq, nr,
                                            W3, b3, lin_w, lin_b, W2, W2p, g, v, c0);
  fill_part_kernel<<<nchunk * 8, 256, 0, stream>>>(src, dst, cursor, colsrc, E, nq, nr);
  agg9_gemm1_kernel<<<nb2, 256, 0, stream>>>(xp, dinv, rows, colsrc, W1, b1, hA, N);
  aggH_kernel<<<(N + 3) / 4, 256, 0, stream>>>(hA, rows, colsrc, g, N);
  gemmz_kernel<<<(N + 63) / 64, 256, 0, stream>>>(g, W2p, dinv, b2, v, zd, N);
  agg1_pool_kernel<<<nb2, 256, 0, stream>>>(zd, dinv, rows, colsrc, batch, gsum, gcnt, N);
  final_kernel<<<1, 64, 0, stream>>>(gsum, gcnt, c0, out, G);
}